// Round 19
// baseline (576.423 us; speedup 1.0000x reference)
//
#include <hip/hip_runtime.h>
#include <hip/hip_bf16.h>

#define NN 100000
#define NE 600000

typedef __bf16 bf16x8 __attribute__((ext_vector_type(8)));
typedef float  f32x4  __attribute__((ext_vector_type(4)));

__device__ __forceinline__ float dot4(float4 a, float4 b){
  return a.x*b.x + a.y*b.y + a.z*b.z + a.w*b.w;
}
// unpack 2 packed bf16 (low = even channel) to floats
__device__ __forceinline__ void bf2f(unsigned v, float& a, float& b){
  union { unsigned u; float f; } ua, ub;
  ua.u = v << 16;
  ub.u = v & 0xFFFF0000u;
  a = ua.f; b = ub.f;
}
__device__ __forceinline__ float4 bf4f(uint2 v){
  float4 r;
  bf2f(v.x, r.x, r.y);
  bf2f(v.y, r.z, r.w);
  return r;
}

// ---------------- CSR build (dst-grouped) ----------------
__global__ void count_edges(const int* __restrict__ dst, int* __restrict__ cnt){
  int e = blockIdx.x*256 + threadIdx.x;
  if (e < NE){
    unsigned d = (unsigned)dst[e];
    if (d < NN) atomicAdd(&cnt[d], 1);
  }
}

__global__ void scan1(const int* __restrict__ cnt, int* __restrict__ offs, int* __restrict__ bsum){
  __shared__ int sh[256];
  const int tid = threadIdx.x;
  const int base = blockIdx.x*2048 + tid*8;
  int pre[8]; int s = 0;
  #pragma unroll
  for (int j=0;j<8;j++){
    int idx = base + j;
    int v = (idx < NN) ? cnt[idx] : 0;
    pre[j] = s; s += v;
  }
  sh[tid] = s;
  __syncthreads();
  for (int d=1; d<256; d<<=1){
    int t = (tid >= d) ? sh[tid-d] : 0;
    __syncthreads();
    sh[tid] += t;
    __syncthreads();
  }
  int off = (tid > 0) ? sh[tid-1] : 0;
  #pragma unroll
  for (int j=0;j<8;j++){
    int idx = base + j;
    if (idx < NN) offs[idx] = off + pre[j];
  }
  if (tid == 255) bsum[blockIdx.x] = sh[255];
}

__global__ void scan2(int* __restrict__ bsum){
  if (threadIdx.x == 0){
    int s = 0;
    for (int i=0;i<49;i++){ int t = bsum[i]; bsum[i] = s; s += t; }
  }
}

__global__ void scan3(int* __restrict__ offs, const int* __restrict__ bsum, int* __restrict__ cursor){
  int i = blockIdx.x*256 + threadIdx.x;
  if (i < NN){
    int v = offs[i] + bsum[i>>11];
    offs[i] = v; cursor[i] = v;
  }
  if (i == 0) offs[NN] = NE;
}

__global__ void fill_csr(const int* __restrict__ src, const int* __restrict__ dst,
                         int* __restrict__ cursor, int* __restrict__ csrsrc){
  int e = blockIdx.x*256 + threadIdx.x;
  if (e < NE){
    unsigned d = (unsigned)dst[e];
    unsigned s = (unsigned)src[e];
    if (d < NN && s < NN){
      int p = atomicAdd(&cursor[d], 1);
      csrsrc[p] = (int)s;
    }
  }
}

// ---------------- weight repack: fp32 W[K][C] -> bf16 hi/lo MFMA fragments ----
__global__ void repack_w(const float* __restrict__ Wg, const float* __restrict__ w1,
                         const float* __restrict__ w2,
                         __bf16* __restrict__ phi, __bf16* __restrict__ plo)
{
  int gid = blockIdx.x*256 + threadIdx.x;
  const float* W; int C; size_t obase; int rem;
  if (gid < 8192)      { W = Wg + (size_t)(gid/2048)*16384; C = 128; obase = (size_t)(gid/2048)*16384; rem = gid % 2048; }
  else if (gid < 10240){ W = w1; C = 128; obase = 65536; rem = gid - 8192; }
  else if (gid < 11264){ W = w2; C = 64;  obase = 81920; rem = gid - 10240; }
  else return;
  const int lane = rem & 63;
  const int tks  = rem >> 6;
  const int ks = tks & 3, t = tks >> 2;
  const int col = t*16 + (lane & 15);
  const int kb  = ks*32 + (lane >> 4)*8;
  const size_t o = obase + (size_t)rem*8;
  #pragma unroll
  for (int j=0;j<8;j++){
    float v = W[(size_t)(kb+j)*C + col];
    __bf16 hb = (__bf16)v;
    phi[o+j] = hb;
    plo[o+j] = (__bf16)(v - (float)hb);
  }
}

// ---------------- input MLP: h = relu(LN(x@w_in+b_in)) ----------------
__global__ __launch_bounds__(256) void input_mlp(const float* __restrict__ x,
    const float* __restrict__ win, const float* __restrict__ b,
    const float* __restrict__ lnw, const float* __restrict__ lnb,
    float* __restrict__ h)
{
  const int tid = threadIdx.x;
  const int g = tid >> 5, l = tid & 31;
  const int n = blockIdx.x*8 + g;
  const float4* W4 = (const float4*)win;
  float xr[6];
  #pragma unroll
  for (int k=0;k<6;k++) xr[k] = x[n*6+k];
  float4 s = ((const float4*)b)[l];
  #pragma unroll
  for (int k=0;k<6;k++){
    float4 w = W4[k*32 + l];
    s.x = fmaf(xr[k], w.x, s.x);
    s.y = fmaf(xr[k], w.y, s.y);
    s.z = fmaf(xr[k], w.z, s.z);
    s.w = fmaf(xr[k], w.w, s.w);
  }
  float sum = s.x+s.y+s.z+s.w;
  float sq  = dot4(s,s);
  #pragma unroll
  for (int o=16;o>=1;o>>=1){ sum += __shfl_xor(sum,o); sq += __shfl_xor(sq,o); }
  float mean = sum*(1.f/128.f);
  float var  = sq*(1.f/128.f) - mean*mean;
  float rr = rsqrtf(var + 1e-5f);
  float4 lw = ((const float4*)lnw)[l];
  float4 lb = ((const float4*)lnb)[l];
  float4 y;
  y.x = fmaxf((s.x-mean)*rr*lw.x + lb.x, 0.f);
  y.y = fmaxf((s.y-mean)*rr*lw.y + lb.y, 0.f);
  y.z = fmaxf((s.z-mean)*rr*lw.z + lb.z, 0.f);
  y.w = fmaxf((s.w-mean)*rr*lw.w + lb.w, 0.f);
  ((float4*)(h + (size_t)n*128))[l] = y;
}

// ---------------- MFMA split-bf16 GEMM: Y = act(LN?(X@W + b)), K=128 ----------
// 256 rows/block: B (hi+lo) staged in LDS ONCE, then each wave processes 4
// chunks of 16 rows reading B via ds_read. Amortizes the staging cost and
// cuts B L2 line-traffic 4x vs 64-row blocks (r18's staging failed because
// only 64 rows amortized it; r17's no-staging was L2 request-bound).
template<int C, bool HAS_BIAS, bool DO_LN, bool DO_RELU, bool GAT, bool OUTP>
__global__ __launch_bounds__(256) void gemm_mfma(const float* __restrict__ X,
    const __bf16* __restrict__ Bhi, const __bf16* __restrict__ Blo,
    const float* __restrict__ bias,
    const float* __restrict__ lnw, const float* __restrict__ lnb,
    const float* __restrict__ asrc, const float* __restrict__ adst,
    float* __restrict__ Y, __bf16* __restrict__ Yb,
    float* __restrict__ als, float* __restrict__ ald,
    const float* __restrict__ w3, const float* __restrict__ b3,
    float* __restrict__ outp)
{
  constexpr int NT = C/16;
  __shared__ __bf16 sBh[128*C];
  __shared__ __bf16 sBl[128*C];
  const int tid = threadIdx.x;
  const int wid = tid >> 6, lane = tid & 63;
  const int lrow = lane & 15, lgrp = lane >> 4;

  // stage B (hi+lo) into LDS, coalesced uint4
  {
    const uint4* gh = (const uint4*)Bhi;
    const uint4* gl = (const uint4*)Blo;
    uint4* sh4 = (uint4*)sBh;
    uint4* sl4 = (uint4*)sBl;
    constexpr int NF = 128*C/8;   // uint4 count
    #pragma unroll 4
    for (int i = tid; i < NF; i += 256){ sh4[i] = gh[i]; sl4[i] = gl[i]; }
  }
  __syncthreads();

  const bf16x8* B8h = (const bf16x8*)sBh;
  const bf16x8* B8l = (const bf16x8*)sBl;
  const int wbase = blockIdx.x*256 + wid*64;

  for (int rc = 0; rc < 4; ++rc){
    const int m0 = wbase + rc*16;

    bf16x8 Ahi[4], Alo[4];
    {
      int row = m0 + lrow; if (row >= NN) row = NN-1;
      const float* Xr = X + (size_t)row*128 + lgrp*8;
      #pragma unroll
      for (int ks=0; ks<4; ks++){
        float4 u0 = *(const float4*)(Xr + ks*32);
        float4 u1 = *(const float4*)(Xr + ks*32 + 4);
        float v[8] = {u0.x,u0.y,u0.z,u0.w,u1.x,u1.y,u1.z,u1.w};
        bf16x8 h8, l8;
        #pragma unroll
        for (int j=0;j<8;j++){
          __bf16 hb = (__bf16)v[j];
          h8[j] = hb;
          l8[j] = (__bf16)(v[j] - (float)hb);
        }
        Ahi[ks] = h8; Alo[ks] = l8;
      }
    }

    f32x4 acc[NT];
    #pragma unroll
    for (int t=0;t<NT;t++){ acc[t] = (f32x4){0.f,0.f,0.f,0.f}; }

    #pragma unroll
    for (int ks=0;ks<4;ks++){
      bf16x8 bh[NT];
      #pragma unroll
      for (int t=0;t<NT;t++) bh[t] = B8h[(t*4+ks)*64 + lane];
      #pragma unroll
      for (int t=0;t<NT;t++)
        acc[t] = __builtin_amdgcn_mfma_f32_16x16x32_bf16(Ahi[ks], bh[t], acc[t], 0,0,0);
      #pragma unroll
      for (int t=0;t<NT;t++)
        acc[t] = __builtin_amdgcn_mfma_f32_16x16x32_bf16(Alo[ks], bh[t], acc[t], 0,0,0);
      #pragma unroll
      for (int t=0;t<NT;t++){
        bf16x8 bl = B8l[(t*4+ks)*64 + lane];
        acc[t] = __builtin_amdgcn_mfma_f32_16x16x32_bf16(Ahi[ks], bl, acc[t], 0,0,0);
      }
    }

    if constexpr (HAS_BIAS){
      #pragma unroll
      for (int t=0;t<NT;t++){
        float bv = bias[t*16 + lrow];
        #pragma unroll
        for (int i=0;i<4;i++) acc[t][i] += bv;
      }
    }

    if constexpr (GAT){
      #pragma unroll
      for (int t=0;t<NT;t++){
        float av = asrc[t*16 + lrow];
        float dv2 = adst[t*16 + lrow];
        float ps[4], pd[4];
        #pragma unroll
        for (int i=0;i<4;i++){
          int n = m0 + lgrp*4 + i;
          if (n < NN) Yb[(size_t)n*C + t*16 + lrow] = (__bf16)acc[t][i];
          ps[i] = acc[t][i]*av; pd[i] = acc[t][i]*dv2;
        }
        #pragma unroll
        for (int off=1; off<16; off<<=1){
          #pragma unroll
          for (int i=0;i<4;i++){
            ps[i] += __shfl_xor(ps[i], off);
            pd[i] += __shfl_xor(pd[i], off);
          }
        }
        if (lrow == 0){
          #pragma unroll
          for (int i=0;i<4;i++){
            int n = m0 + lgrp*4 + i;
            if (n < NN){ als[n*8 + t] = ps[i]; ald[n*8 + t] = pd[i]; }
          }
        }
      }
    } else {
      if constexpr (DO_LN){
        float s[4] = {0,0,0,0}, q[4] = {0,0,0,0};
        #pragma unroll
        for (int t=0;t<NT;t++){
          #pragma unroll
          for (int i=0;i<4;i++){ s[i] += acc[t][i]; q[i] += acc[t][i]*acc[t][i]; }
        }
        #pragma unroll
        for (int off=1; off<16; off<<=1){
          #pragma unroll
          for (int i=0;i<4;i++){ s[i] += __shfl_xor(s[i], off); q[i] += __shfl_xor(q[i], off); }
        }
        float mean[4], rr[4];
        #pragma unroll
        for (int i=0;i<4;i++){
          mean[i] = s[i]*(1.0f/C);
          float var = q[i]*(1.0f/C) - mean[i]*mean[i];
          rr[i] = rsqrtf(var + 1e-5f);
        }
        #pragma unroll
        for (int t=0;t<NT;t++){
          float lw = lnw[t*16 + lrow], lb = lnb[t*16 + lrow];
          #pragma unroll
          for (int i=0;i<4;i++){
            float v = (acc[t][i]-mean[i])*rr[i]*lw + lb;
            if constexpr (DO_RELU) v = fmaxf(v, 0.f);
            acc[t][i] = v;
          }
        }
      } else if constexpr (DO_RELU){
        #pragma unroll
        for (int t=0;t<NT;t++){
          #pragma unroll
          for (int i=0;i<4;i++) acc[t][i] = fmaxf(acc[t][i], 0.f);
        }
      }
      if constexpr (OUTP){
        float4 w3r[NT];
        #pragma unroll
        for (int t=0;t<NT;t++) w3r[t] = ((const float4*)w3)[t*16 + lrow];
        float4 b3v = *(const float4*)b3;
        #pragma unroll
        for (int i=0;i<4;i++){
          float4 po = make_float4(0.f,0.f,0.f,0.f);
          #pragma unroll
          for (int t=0;t<NT;t++){
            po.x = fmaf(acc[t][i], w3r[t].x, po.x);
            po.y = fmaf(acc[t][i], w3r[t].y, po.y);
            po.z = fmaf(acc[t][i], w3r[t].z, po.z);
            po.w = fmaf(acc[t][i], w3r[t].w, po.w);
          }
          #pragma unroll
          for (int off=1; off<16; off<<=1){
            po.x += __shfl_xor(po.x, off);
            po.y += __shfl_xor(po.y, off);
            po.z += __shfl_xor(po.z, off);
            po.w += __shfl_xor(po.w, off);
          }
          if (lrow == 0){
            int n = m0 + lgrp*4 + i;
            if (n < NN){
              float4 o;
              o.x = po.x + b3v.x; o.y = po.y + b3v.y;
              o.z = po.z + b3v.z; o.w = po.w + b3v.w;
              ((float4*)outp)[n] = o;
            }
          }
        }
      } else {
        #pragma unroll
        for (int t=0;t<NT;t++){
          #pragma unroll
          for (int i=0;i<4;i++){
            int n = m0 + lgrp*4 + i;
            if (n < NN) Y[(size_t)n*C + t*16 + lrow] = acc[t][i];
          }
        }
      }
    }
  }
}

// ---------------- per-node softmax + aggregate + LN + residual ----------------
// Two nodes per wave: each 32-lane group owns ONE node (4 channels/lane via
// one uint2 bf16 load, head hh = sl>>2). Private per-lane exp, unrolled
// independent loads, zero cross-lane ops in the edge loop.
__global__ __launch_bounds__(256) void gat_aggregate(
    const __bf16* __restrict__ xw, const float* __restrict__ als, const float* __restrict__ ald,
    const int* __restrict__ offs, const int* __restrict__ csrsrc,
    const float* __restrict__ bg, const float* __restrict__ lnw, const float* __restrict__ lnb,
    float* __restrict__ h)
{
  const int tid = threadIdx.x;
  const int grp = tid >> 5, sl = tid & 31;
  const int n = blockIdx.x*8 + grp;
  const int hh = sl >> 2;                   // head of channels 4sl..4sl+3
  const float ad = ald[n*8 + hh];
  const uint2* xw64 = (const uint2*)xw;     // 4 bf16 per uint2; node row = 32 uint2

  // self-loop
  float t = als[n*8 + hh] + ad; t = t > 0.f ? t : 0.2f*t;
  float pp = __expf(t);
  float s = pp;
  float4 xv = bf4f(xw64[(unsigned)n*32u + sl]);
  float4 acc;
  acc.x = pp*xv.x; acc.y = pp*xv.y; acc.z = pp*xv.z; acc.w = pp*xv.w;

  const int start = offs[n], end = offs[n+1];
  int e = start;
  for (; e+4 <= end; e += 4){
    int s4[4]; float a[4]; uint2 x2[4];
    #pragma unroll
    for (int j=0;j<4;j++) s4[j] = csrsrc[e+j];
    #pragma unroll
    for (int j=0;j<4;j++){
      a[j]  = als[s4[j]*8 + hh];
      x2[j] = xw64[(unsigned)s4[j]*32u + sl];
    }
    #pragma unroll
    for (int j=0;j<4;j++){
      float u = a[j] + ad; u = u > 0.f ? u : 0.2f*u;
      float q = __expf(u);
      s += q;
      float4 m = bf4f(x2[j]);
      acc.x = fmaf(q, m.x, acc.x);
      acc.y = fmaf(q, m.y, acc.y);
      acc.z = fmaf(q, m.z, acc.z);
      acc.w = fmaf(q, m.w, acc.w);
    }
  }
  if (e+2 <= end){
    int sA = csrsrc[e], sB = csrsrc[e+1];
    float aA = als[sA*8+hh], aB = als[sB*8+hh];
    uint2 xA = xw64[(unsigned)sA*32u + sl];
    uint2 xB = xw64[(unsigned)sB*32u + sl];
    float u;
    u = aA+ad; u = u>0.f?u:0.2f*u; float qA = __expf(u);
    u = aB+ad; u = u>0.f?u:0.2f*u; float qB = __expf(u);
    s += qA+qB;
    float4 mA = bf4f(xA), mB = bf4f(xB);
    acc.x = fmaf(qA, mA.x, fmaf(qB, mB.x, acc.x));
    acc.y = fmaf(qA, mA.y, fmaf(qB, mB.y, acc.y));
    acc.z = fmaf(qA, mA.z, fmaf(qB, mB.z, acc.z));
    acc.w = fmaf(qA, mA.w, fmaf(qB, mB.w, acc.w));
    e += 2;
  }
  if (e < end){
    int sA = csrsrc[e];
    float aA = als[sA*8+hh];
    uint2 xA = xw64[(unsigned)sA*32u + sl];
    float u = aA+ad; u = u>0.f?u:0.2f*u; float qA = __expf(u);
    s += qA;
    float4 mA = bf4f(xA);
    acc.x = fmaf(qA, mA.x, acc.x);
    acc.y = fmaf(qA, mA.y, acc.y);
    acc.z = fmaf(qA, mA.z, acc.z);
    acc.w = fmaf(qA, mA.w, acc.w);
  }

  float4 bgv = ((const float4*)bg)[sl];
  float inv = 1.0f/s;
  float4 val;
  val.x = acc.x*inv + bgv.x;
  val.y = acc.y*inv + bgv.y;
  val.z = acc.z*inv + bgv.z;
  val.w = acc.w*inv + bgv.w;
  // LayerNorm across 128 channels: butterfly over the 32 lanes of this group
  float sum = val.x+val.y+val.z+val.w;
  float sq  = dot4(val,val);
  #pragma unroll
  for (int off=16; off>=1; off>>=1){ sum += __shfl_xor(sum,off); sq += __shfl_xor(sq,off); }
  float mean = sum*(1.f/128.f);
  float var  = sq*(1.f/128.f) - mean*mean;
  float rr = rsqrtf(var + 1e-5f);
  float4 lw = ((const float4*)lnw)[sl];
  float4 lb = ((const float4*)lnb)[sl];
  float4* hp = (float4*)(h + (size_t)n*128) + sl;
  float4 hv = *hp;
  hv.x += fmaxf((val.x-mean)*rr*lw.x + lb.x, 0.f);
  hv.y += fmaxf((val.y-mean)*rr*lw.y + lb.y, 0.f);
  hv.z += fmaxf((val.z-mean)*rr*lw.z + lb.z, 0.f);
  hv.w += fmaxf((val.w-mean)*rr*lw.w + lb.w, 0.f);
  *hp = hv;
}

extern "C" void kernel_launch(void* const* d_in, const int* in_sizes, int n_in,
                              void* d_out, int out_size, void* d_ws, size_t ws_size,
                              hipStream_t stream)
{
  const float* x       = (const float*)d_in[0];
  const int*   ei      = (const int*)d_in[1];
  const float* w_in    = (const float*)d_in[2];
  const float* b_in    = (const float*)d_in[3];
  const float* ln_in_w = (const float*)d_in[4];
  const float* ln_in_b = (const float*)d_in[5];
  const float* Wg      = (const float*)d_in[6];
  const float* a_src   = (const float*)d_in[7];
  const float* a_dst   = (const float*)d_in[8];
  const float* bg      = (const float*)d_in[9];
  const float* lnw     = (const float*)d_in[10];
  const float* lnb     = (const float*)d_in[11];
  const float* w1      = (const float*)d_in[12];
  const float* b1      = (const float*)d_in[13];
  const float* lnow    = (const float*)d_in[14];
  const float* lnob    = (const float*)d_in[15];
  const float* w2      = (const float*)d_in[16];
  const float* b2      = (const float*)d_in[17];
  const float* w3      = (const float*)d_in[18];
  const float* b3      = (const float*)d_in[19];
  float* out = (float*)d_out;

  char* p = (char*)d_ws;
  auto carve = [&](size_t bytes)->void*{
    void* r = (void*)p; p += (bytes + 255) & ~(size_t)255; return r;
  };
  float* h    = (float*)carve((size_t)NN*128*4);
  float* xw   = (float*)carve((size_t)NN*128*4);   // fp32 o1 output
  __bf16* xwb = (__bf16*)carve((size_t)NN*128*2);  // bf16 GAT messages
  float* als  = (float*)carve((size_t)NN*8*4);
  float* ald  = (float*)carve((size_t)NN*8*4);
  int* offs   = (int*)carve((size_t)(NN+1)*4);
  int* cursor = (int*)carve((size_t)NN*4);
  int* cnt    = (int*)carve((size_t)NN*4);
  int* csrsrc = (int*)carve((size_t)NE*4);
  int* bsum   = (int*)carve(64*4);
  __bf16* pWhi = (__bf16*)carve((size_t)90112*2);
  __bf16* pWlo = (__bf16*)carve((size_t)90112*2);

  const int* esrc = ei;
  const int* edst = ei + NE;

  // one-time weight repack into MFMA fragment layout (bf16 hi/lo)
  repack_w<<<44, 256, 0, stream>>>(Wg, w1, w2, pWhi, pWlo);

  hipMemsetAsync(cnt, 0, (size_t)NN*4, stream);
  count_edges<<<(NE+255)/256, 256, 0, stream>>>(edst, cnt);
  scan1<<<49, 256, 0, stream>>>(cnt, offs, bsum);
  scan2<<<1, 64, 0, stream>>>(bsum);
  scan3<<<(NN+255)/256, 256, 0, stream>>>(offs, bsum, cursor);
  fill_csr<<<(NE+255)/256, 256, 0, stream>>>(esrc, edst, cursor, csrsrc);

  input_mlp<<<NN/8, 256, 0, stream>>>(x, w_in, b_in, ln_in_w, ln_in_b, h);

  const int GRIDB = (NN + 255) / 256;   // 391 blocks x 256 rows
  for (int i=0;i<4;i++){
    gemm_mfma<128,false,false,false,true,false><<<GRIDB, 256, 0, stream>>>(
        h, pWhi + (size_t)i*16384, pWlo + (size_t)i*16384, nullptr, nullptr, nullptr,
        a_src + i*128, a_dst + i*128, nullptr, xwb, als, ald, nullptr, nullptr, nullptr);
    gat_aggregate<<<NN/8, 256, 0, stream>>>(xwb, als, ald, offs, csrsrc,
        bg + i*128, lnw + i*128, lnb + i*128, h);
  }

  gemm_mfma<128,true,true,true,false,false><<<GRIDB, 256, 0, stream>>>(
      h, pWhi + 65536, pWlo + 65536, b1, lnow, lnob, nullptr, nullptr, xw, nullptr,
      nullptr, nullptr, nullptr, nullptr, nullptr);
  gemm_mfma<64,true,false,true,false,true><<<GRIDB, 256, 0, stream>>>(
      xw, pWhi + 81920, pWlo + 81920, b2, nullptr, nullptr, nullptr, nullptr, nullptr, nullptr,
      nullptr, nullptr, w3, b3, out);
}

// Round 20
// 486.876 us; speedup vs baseline: 1.1839x; 1.1839x over previous
//
#include <hip/hip_runtime.h>
#include <hip/hip_bf16.h>

#define NN 100000
#define NE 600000

typedef __bf16 bf16x8 __attribute__((ext_vector_type(8)));
typedef float  f32x4  __attribute__((ext_vector_type(4)));

__device__ __forceinline__ float dot4(float4 a, float4 b){
  return a.x*b.x + a.y*b.y + a.z*b.z + a.w*b.w;
}
// unpack 2 packed bf16 (low = even channel) to floats
__device__ __forceinline__ void bf2f(unsigned v, float& a, float& b){
  union { unsigned u; float f; } ua, ub;
  ua.u = v << 16;
  ub.u = v & 0xFFFF0000u;
  a = ua.f; b = ub.f;
}
__device__ __forceinline__ float4 bf4f(uint2 v){
  float4 r;
  bf2f(v.x, r.x, r.y);
  bf2f(v.y, r.z, r.w);
  return r;
}

// ---------------- CSR build (dst-grouped) ----------------
__global__ void count_edges(const int* __restrict__ dst, int* __restrict__ cnt){
  int e = blockIdx.x*256 + threadIdx.x;
  if (e < NE){
    unsigned d = (unsigned)dst[e];
    if (d < NN) atomicAdd(&cnt[d], 1);
  }
}

__global__ void scan1(const int* __restrict__ cnt, int* __restrict__ offs, int* __restrict__ bsum){
  __shared__ int sh[256];
  const int tid = threadIdx.x;
  const int base = blockIdx.x*2048 + tid*8;
  int pre[8]; int s = 0;
  #pragma unroll
  for (int j=0;j<8;j++){
    int idx = base + j;
    int v = (idx < NN) ? cnt[idx] : 0;
    pre[j] = s; s += v;
  }
  sh[tid] = s;
  __syncthreads();
  for (int d=1; d<256; d<<=1){
    int t = (tid >= d) ? sh[tid-d] : 0;
    __syncthreads();
    sh[tid] += t;
    __syncthreads();
  }
  int off = (tid > 0) ? sh[tid-1] : 0;
  #pragma unroll
  for (int j=0;j<8;j++){
    int idx = base + j;
    if (idx < NN) offs[idx] = off + pre[j];
  }
  if (tid == 255) bsum[blockIdx.x] = sh[255];
}

__global__ void scan2(int* __restrict__ bsum){
  if (threadIdx.x == 0){
    int s = 0;
    for (int i=0;i<49;i++){ int t = bsum[i]; bsum[i] = s; s += t; }
  }
}

__global__ void scan3(int* __restrict__ offs, const int* __restrict__ bsum, int* __restrict__ cursor){
  int i = blockIdx.x*256 + threadIdx.x;
  if (i < NN){
    int v = offs[i] + bsum[i>>11];
    offs[i] = v; cursor[i] = v;
  }
  if (i == 0) offs[NN] = NE;
}

__global__ void fill_csr(const int* __restrict__ src, const int* __restrict__ dst,
                         int* __restrict__ cursor, int* __restrict__ csrsrc){
  int e = blockIdx.x*256 + threadIdx.x;
  if (e < NE){
    unsigned d = (unsigned)dst[e];
    unsigned s = (unsigned)src[e];
    if (d < NN && s < NN){
      int p = atomicAdd(&cursor[d], 1);
      csrsrc[p] = (int)s;
    }
  }
}

// ---------------- weight repack: fp32 W[K][C] -> bf16 hi/lo MFMA fragments ----
__global__ void repack_w(const float* __restrict__ Wg, const float* __restrict__ w1,
                         const float* __restrict__ w2,
                         __bf16* __restrict__ phi, __bf16* __restrict__ plo)
{
  int gid = blockIdx.x*256 + threadIdx.x;
  const float* W; int C; size_t obase; int rem;
  if (gid < 8192)      { W = Wg + (size_t)(gid/2048)*16384; C = 128; obase = (size_t)(gid/2048)*16384; rem = gid % 2048; }
  else if (gid < 10240){ W = w1; C = 128; obase = 65536; rem = gid - 8192; }
  else if (gid < 11264){ W = w2; C = 64;  obase = 81920; rem = gid - 10240; }
  else return;
  const int lane = rem & 63;
  const int tks  = rem >> 6;
  const int ks = tks & 3, t = tks >> 2;
  const int col = t*16 + (lane & 15);
  const int kb  = ks*32 + (lane >> 4)*8;
  const size_t o = obase + (size_t)rem*8;
  #pragma unroll
  for (int j=0;j<8;j++){
    float v = W[(size_t)(kb+j)*C + col];
    __bf16 hb = (__bf16)v;
    phi[o+j] = hb;
    plo[o+j] = (__bf16)(v - (float)hb);
  }
}

// ---------------- input MLP: h = relu(LN(x@w_in+b_in)) ----------------
__global__ __launch_bounds__(256) void input_mlp(const float* __restrict__ x,
    const float* __restrict__ win, const float* __restrict__ b,
    const float* __restrict__ lnw, const float* __restrict__ lnb,
    float* __restrict__ h)
{
  const int tid = threadIdx.x;
  const int g = tid >> 5, l = tid & 31;
  const int n = blockIdx.x*8 + g;
  const float4* W4 = (const float4*)win;
  float xr[6];
  #pragma unroll
  for (int k=0;k<6;k++) xr[k] = x[n*6+k];
  float4 s = ((const float4*)b)[l];
  #pragma unroll
  for (int k=0;k<6;k++){
    float4 w = W4[k*32 + l];
    s.x = fmaf(xr[k], w.x, s.x);
    s.y = fmaf(xr[k], w.y, s.y);
    s.z = fmaf(xr[k], w.z, s.z);
    s.w = fmaf(xr[k], w.w, s.w);
  }
  float sum = s.x+s.y+s.z+s.w;
  float sq  = dot4(s,s);
  #pragma unroll
  for (int o=16;o>=1;o>>=1){ sum += __shfl_xor(sum,o); sq += __shfl_xor(sq,o); }
  float mean = sum*(1.f/128.f);
  float var  = sq*(1.f/128.f) - mean*mean;
  float rr = rsqrtf(var + 1e-5f);
  float4 lw = ((const float4*)lnw)[l];
  float4 lb = ((const float4*)lnb)[l];
  float4 y;
  y.x = fmaxf((s.x-mean)*rr*lw.x + lb.x, 0.f);
  y.y = fmaxf((s.y-mean)*rr*lw.y + lb.y, 0.f);
  y.z = fmaxf((s.z-mean)*rr*lw.z + lb.z, 0.f);
  y.w = fmaxf((s.w-mean)*rr*lw.w + lb.w, 0.f);
  ((float4*)(h + (size_t)n*128))[l] = y;
}

// ---------------- MFMA split-bf16 GEMM: Y = act(LN?(X@W + b)), K=128 ----------
// SPLIT (GAT only): each wave handles 16 rows x 64 cols (NT=4) -> half the
// per-wave work, double the wave count (12500) for latency hiding. Safe for
// GAT because its epilogue reductions are per-head (= per 16-col tile, within
// wave). o1 (full-row LN) and o2 (full-row OUTP) keep full-width waves.
template<int C, bool HAS_BIAS, bool DO_LN, bool DO_RELU, bool GAT, bool OUTP, bool SPLIT>
__global__ __launch_bounds__(256) void gemm_mfma(const float* __restrict__ X,
    const __bf16* __restrict__ Bhi, const __bf16* __restrict__ Blo,
    const float* __restrict__ bias,
    const float* __restrict__ lnw, const float* __restrict__ lnb,
    const float* __restrict__ asrc, const float* __restrict__ adst,
    float* __restrict__ Y, __bf16* __restrict__ Yb,
    float* __restrict__ als, float* __restrict__ ald,
    const float* __restrict__ w3, const float* __restrict__ b3,
    float* __restrict__ outp)
{
  constexpr int NT = SPLIT ? C/32 : C/16;
  const int tid = threadIdx.x;
  const int wid = tid >> 6, lane = tid & 63;
  const int lrow = lane & 15, lgrp = lane >> 4;
  const int m0    = SPLIT ? (blockIdx.x*32 + (wid>>1)*16) : ((blockIdx.x*4 + wid)*16);
  const int colt0 = SPLIT ? (wid & 1)*NT : 0;   // starting 16-col tile index

  bf16x8 Ahi[4], Alo[4];
  {
    int row = m0 + lrow; if (row >= NN) row = NN-1;
    const float* Xr = X + (size_t)row*128 + lgrp*8;
    #pragma unroll
    for (int ks=0; ks<4; ks++){
      float4 u0 = *(const float4*)(Xr + ks*32);
      float4 u1 = *(const float4*)(Xr + ks*32 + 4);
      float v[8] = {u0.x,u0.y,u0.z,u0.w,u1.x,u1.y,u1.z,u1.w};
      bf16x8 h8, l8;
      #pragma unroll
      for (int j=0;j<8;j++){
        __bf16 hb = (__bf16)v[j];
        h8[j] = hb;
        l8[j] = (__bf16)(v[j] - (float)hb);
      }
      Ahi[ks] = h8; Alo[ks] = l8;
    }
  }

  f32x4 acc[NT];
  #pragma unroll
  for (int t=0;t<NT;t++){ acc[t] = (f32x4){0.f,0.f,0.f,0.f}; }

  const bf16x8* B8h = (const bf16x8*)Bhi;
  const bf16x8* B8l = (const bf16x8*)Blo;
  #pragma unroll
  for (int ks=0;ks<4;ks++){
    bf16x8 bh[NT];
    #pragma unroll
    for (int t=0;t<NT;t++) bh[t] = B8h[((colt0+t)*4+ks)*64 + lane];
    #pragma unroll
    for (int t=0;t<NT;t++)
      acc[t] = __builtin_amdgcn_mfma_f32_16x16x32_bf16(Ahi[ks], bh[t], acc[t], 0,0,0);
    #pragma unroll
    for (int t=0;t<NT;t++)
      acc[t] = __builtin_amdgcn_mfma_f32_16x16x32_bf16(Alo[ks], bh[t], acc[t], 0,0,0);
    #pragma unroll
    for (int t=0;t<NT;t++){
      bf16x8 bl = B8l[((colt0+t)*4+ks)*64 + lane];
      acc[t] = __builtin_amdgcn_mfma_f32_16x16x32_bf16(Ahi[ks], bl, acc[t], 0,0,0);
    }
  }

  if constexpr (HAS_BIAS){
    #pragma unroll
    for (int t=0;t<NT;t++){
      float bv = bias[(colt0+t)*16 + lrow];
      #pragma unroll
      for (int i=0;i<4;i++) acc[t][i] += bv;
    }
  }

  if constexpr (GAT){
    #pragma unroll
    for (int t=0;t<NT;t++){
      float av = asrc[(colt0+t)*16 + lrow];
      float dv2 = adst[(colt0+t)*16 + lrow];
      float ps[4], pd[4];
      #pragma unroll
      for (int i=0;i<4;i++){
        int n = m0 + lgrp*4 + i;
        if (n < NN) Yb[(size_t)n*C + (colt0+t)*16 + lrow] = (__bf16)acc[t][i];
        ps[i] = acc[t][i]*av; pd[i] = acc[t][i]*dv2;
      }
      #pragma unroll
      for (int off=1; off<16; off<<=1){
        #pragma unroll
        for (int i=0;i<4;i++){
          ps[i] += __shfl_xor(ps[i], off);
          pd[i] += __shfl_xor(pd[i], off);
        }
      }
      if (lrow == 0){
        #pragma unroll
        for (int i=0;i<4;i++){
          int n = m0 + lgrp*4 + i;
          if (n < NN){ als[n*8 + colt0 + t] = ps[i]; ald[n*8 + colt0 + t] = pd[i]; }
        }
      }
    }
  } else {
    if constexpr (DO_LN){
      float s[4] = {0,0,0,0}, q[4] = {0,0,0,0};
      #pragma unroll
      for (int t=0;t<NT;t++){
        #pragma unroll
        for (int i=0;i<4;i++){ s[i] += acc[t][i]; q[i] += acc[t][i]*acc[t][i]; }
      }
      #pragma unroll
      for (int off=1; off<16; off<<=1){
        #pragma unroll
        for (int i=0;i<4;i++){ s[i] += __shfl_xor(s[i], off); q[i] += __shfl_xor(q[i], off); }
      }
      float mean[4], rr[4];
      #pragma unroll
      for (int i=0;i<4;i++){
        mean[i] = s[i]*(1.0f/C);
        float var = q[i]*(1.0f/C) - mean[i]*mean[i];
        rr[i] = rsqrtf(var + 1e-5f);
      }
      #pragma unroll
      for (int t=0;t<NT;t++){
        float lw = lnw[t*16 + lrow], lb = lnb[t*16 + lrow];
        #pragma unroll
        for (int i=0;i<4;i++){
          float v = (acc[t][i]-mean[i])*rr[i]*lw + lb;
          if constexpr (DO_RELU) v = fmaxf(v, 0.f);
          acc[t][i] = v;
        }
      }
    } else if constexpr (DO_RELU){
      #pragma unroll
      for (int t=0;t<NT;t++){
        #pragma unroll
        for (int i=0;i<4;i++) acc[t][i] = fmaxf(acc[t][i], 0.f);
      }
    }
    if constexpr (OUTP){
      float4 w3r[NT];
      #pragma unroll
      for (int t=0;t<NT;t++) w3r[t] = ((const float4*)w3)[t*16 + lrow];
      float4 b3v = *(const float4*)b3;
      #pragma unroll
      for (int i=0;i<4;i++){
        float4 po = make_float4(0.f,0.f,0.f,0.f);
        #pragma unroll
        for (int t=0;t<NT;t++){
          po.x = fmaf(acc[t][i], w3r[t].x, po.x);
          po.y = fmaf(acc[t][i], w3r[t].y, po.y);
          po.z = fmaf(acc[t][i], w3r[t].z, po.z);
          po.w = fmaf(acc[t][i], w3r[t].w, po.w);
        }
        #pragma unroll
        for (int off=1; off<16; off<<=1){
          po.x += __shfl_xor(po.x, off);
          po.y += __shfl_xor(po.y, off);
          po.z += __shfl_xor(po.z, off);
          po.w += __shfl_xor(po.w, off);
        }
        if (lrow == 0){
          int n = m0 + lgrp*4 + i;
          if (n < NN){
            float4 o;
            o.x = po.x + b3v.x; o.y = po.y + b3v.y;
            o.z = po.z + b3v.z; o.w = po.w + b3v.w;
            ((float4*)outp)[n] = o;
          }
        }
      }
    } else {
      #pragma unroll
      for (int t=0;t<NT;t++){
        #pragma unroll
        for (int i=0;i<4;i++){
          int n = m0 + lgrp*4 + i;
          if (n < NN) Y[(size_t)n*C + t*16 + lrow] = acc[t][i];
        }
      }
    }
  }
}

// ---------------- per-node softmax + aggregate + LN + residual ----------------
// Two nodes per wave: each 32-lane group owns ONE node (4 channels/lane via
// one uint2 bf16 load, head hh = sl>>2). Private per-lane exp, unrolled
// independent loads, zero cross-lane ops in the edge loop.
__global__ __launch_bounds__(256) void gat_aggregate(
    const __bf16* __restrict__ xw, const float* __restrict__ als, const float* __restrict__ ald,
    const int* __restrict__ offs, const int* __restrict__ csrsrc,
    const float* __restrict__ bg, const float* __restrict__ lnw, const float* __restrict__ lnb,
    float* __restrict__ h)
{
  const int tid = threadIdx.x;
  const int grp = tid >> 5, sl = tid & 31;
  const int n = blockIdx.x*8 + grp;
  const int hh = sl >> 2;                   // head of channels 4sl..4sl+3
  const float ad = ald[n*8 + hh];
  const uint2* xw64 = (const uint2*)xw;     // 4 bf16 per uint2; node row = 32 uint2

  // self-loop
  float t = als[n*8 + hh] + ad; t = t > 0.f ? t : 0.2f*t;
  float pp = __expf(t);
  float s = pp;
  float4 xv = bf4f(xw64[(unsigned)n*32u + sl]);
  float4 acc;
  acc.x = pp*xv.x; acc.y = pp*xv.y; acc.z = pp*xv.z; acc.w = pp*xv.w;

  const int start = offs[n], end = offs[n+1];
  int e = start;
  for (; e+4 <= end; e += 4){
    int s4[4]; float a[4]; uint2 x2[4];
    #pragma unroll
    for (int j=0;j<4;j++) s4[j] = csrsrc[e+j];
    #pragma unroll
    for (int j=0;j<4;j++){
      a[j]  = als[s4[j]*8 + hh];
      x2[j] = xw64[(unsigned)s4[j]*32u + sl];
    }
    #pragma unroll
    for (int j=0;j<4;j++){
      float u = a[j] + ad; u = u > 0.f ? u : 0.2f*u;
      float q = __expf(u);
      s += q;
      float4 m = bf4f(x2[j]);
      acc.x = fmaf(q, m.x, acc.x);
      acc.y = fmaf(q, m.y, acc.y);
      acc.z = fmaf(q, m.z, acc.z);
      acc.w = fmaf(q, m.w, acc.w);
    }
  }
  if (e+2 <= end){
    int sA = csrsrc[e], sB = csrsrc[e+1];
    float aA = als[sA*8+hh], aB = als[sB*8+hh];
    uint2 xA = xw64[(unsigned)sA*32u + sl];
    uint2 xB = xw64[(unsigned)sB*32u + sl];
    float u;
    u = aA+ad; u = u>0.f?u:0.2f*u; float qA = __expf(u);
    u = aB+ad; u = u>0.f?u:0.2f*u; float qB = __expf(u);
    s += qA+qB;
    float4 mA = bf4f(xA), mB = bf4f(xB);
    acc.x = fmaf(qA, mA.x, fmaf(qB, mB.x, acc.x));
    acc.y = fmaf(qA, mA.y, fmaf(qB, mB.y, acc.y));
    acc.z = fmaf(qA, mA.z, fmaf(qB, mB.z, acc.z));
    acc.w = fmaf(qA, mA.w, fmaf(qB, mB.w, acc.w));
    e += 2;
  }
  if (e < end){
    int sA = csrsrc[e];
    float aA = als[sA*8+hh];
    uint2 xA = xw64[(unsigned)sA*32u + sl];
    float u = aA+ad; u = u>0.f?u:0.2f*u; float qA = __expf(u);
    s += qA;
    float4 mA = bf4f(xA);
    acc.x = fmaf(qA, mA.x, acc.x);
    acc.y = fmaf(qA, mA.y, acc.y);
    acc.z = fmaf(qA, mA.z, acc.z);
    acc.w = fmaf(qA, mA.w, acc.w);
  }

  float4 bgv = ((const float4*)bg)[sl];
  float inv = 1.0f/s;
  float4 val;
  val.x = acc.x*inv + bgv.x;
  val.y = acc.y*inv + bgv.y;
  val.z = acc.z*inv + bgv.z;
  val.w = acc.w*inv + bgv.w;
  // LayerNorm across 128 channels: butterfly over the 32 lanes of this group
  float sum = val.x+val.y+val.z+val.w;
  float sq  = dot4(val,val);
  #pragma unroll
  for (int off=16; off>=1; off>>=1){ sum += __shfl_xor(sum,off); sq += __shfl_xor(sq,off); }
  float mean = sum*(1.f/128.f);
  float var  = sq*(1.f/128.f) - mean*mean;
  float rr = rsqrtf(var + 1e-5f);
  float4 lw = ((const float4*)lnw)[sl];
  float4 lb = ((const float4*)lnb)[sl];
  float4* hp = (float4*)(h + (size_t)n*128) + sl;
  float4 hv = *hp;
  hv.x += fmaxf((val.x-mean)*rr*lw.x + lb.x, 0.f);
  hv.y += fmaxf((val.y-mean)*rr*lw.y + lb.y, 0.f);
  hv.z += fmaxf((val.z-mean)*rr*lw.z + lb.z, 0.f);
  hv.w += fmaxf((val.w-mean)*rr*lw.w + lb.w, 0.f);
  *hp = hv;
}

extern "C" void kernel_launch(void* const* d_in, const int* in_sizes, int n_in,
                              void* d_out, int out_size, void* d_ws, size_t ws_size,
                              hipStream_t stream)
{
  const float* x       = (const float*)d_in[0];
  const int*   ei      = (const int*)d_in[1];
  const float* w_in    = (const float*)d_in[2];
  const float* b_in    = (const float*)d_in[3];
  const float* ln_in_w = (const float*)d_in[4];
  const float* ln_in_b = (const float*)d_in[5];
  const float* Wg      = (const float*)d_in[6];
  const float* a_src   = (const float*)d_in[7];
  const float* a_dst   = (const float*)d_in[8];
  const float* bg      = (const float*)d_in[9];
  const float* lnw     = (const float*)d_in[10];
  const float* lnb     = (const float*)d_in[11];
  const float* w1      = (const float*)d_in[12];
  const float* b1      = (const float*)d_in[13];
  const float* lnow    = (const float*)d_in[14];
  const float* lnob    = (const float*)d_in[15];
  const float* w2      = (const float*)d_in[16];
  const float* b2      = (const float*)d_in[17];
  const float* w3      = (const float*)d_in[18];
  const float* b3      = (const float*)d_in[19];
  float* out = (float*)d_out;

  char* p = (char*)d_ws;
  auto carve = [&](size_t bytes)->void*{
    void* r = (void*)p; p += (bytes + 255) & ~(size_t)255; return r;
  };
  float* h    = (float*)carve((size_t)NN*128*4);
  float* xw   = (float*)carve((size_t)NN*128*4);   // fp32 o1 output
  __bf16* xwb = (__bf16*)carve((size_t)NN*128*2);  // bf16 GAT messages
  float* als  = (float*)carve((size_t)NN*8*4);
  float* ald  = (float*)carve((size_t)NN*8*4);
  int* offs   = (int*)carve((size_t)(NN+1)*4);
  int* cursor = (int*)carve((size_t)NN*4);
  int* cnt    = (int*)carve((size_t)NN*4);
  int* csrsrc = (int*)carve((size_t)NE*4);
  int* bsum   = (int*)carve(64*4);
  __bf16* pWhi = (__bf16*)carve((size_t)90112*2);
  __bf16* pWlo = (__bf16*)carve((size_t)90112*2);

  const int* esrc = ei;
  const int* edst = ei + NE;

  // one-time weight repack into MFMA fragment layout (bf16 hi/lo)
  repack_w<<<44, 256, 0, stream>>>(Wg, w1, w2, pWhi, pWlo);

  hipMemsetAsync(cnt, 0, (size_t)NN*4, stream);
  count_edges<<<(NE+255)/256, 256, 0, stream>>>(edst, cnt);
  scan1<<<49, 256, 0, stream>>>(cnt, offs, bsum);
  scan2<<<1, 64, 0, stream>>>(bsum);
  scan3<<<(NN+255)/256, 256, 0, stream>>>(offs, bsum, cursor);
  fill_csr<<<(NE+255)/256, 256, 0, stream>>>(esrc, edst, cursor, csrsrc);

  input_mlp<<<NN/8, 256, 0, stream>>>(x, w_in, b_in, ln_in_w, ln_in_b, h);

  const int GRID  = (NN + 63) / 64;   // 1563 (full-width waves)
  const int GRIDS = (NN + 31) / 32;   // 3125 (col-split waves)
  for (int i=0;i<4;i++){
    gemm_mfma<128,false,false,false,true,false,true><<<GRIDS, 256, 0, stream>>>(
        h, pWhi + (size_t)i*16384, pWlo + (size_t)i*16384, nullptr, nullptr, nullptr,
        a_src + i*128, a_dst + i*128, nullptr, xwb, als, ald, nullptr, nullptr, nullptr);
    gat_aggregate<<<NN/8, 256, 0, stream>>>(xwb, als, ald, offs, csrsrc,
        bg + i*128, lnw + i*128, lnb + i*128, h);
  }

  gemm_mfma<128,true,true,true,false,false,false><<<GRID, 256, 0, stream>>>(
      h, pWhi + 65536, pWlo + 65536, b1, lnow, lnob, nullptr, nullptr, xw, nullptr,
      nullptr, nullptr, nullptr, nullptr, nullptr);
  gemm_mfma<64,true,false,true,false,true,false><<<GRID, 256, 0, stream>>>(
      xw, pWhi + 81920, pWlo + 81920, b2, nullptr, nullptr, nullptr, nullptr, nullptr, nullptr,
      nullptr, nullptr, w3, b3, out);
}